// Round 8
// baseline (360.148 us; speedup 1.0000x reference)
//
#include <hip/hip_runtime.h>
#include <hip/hip_bf16.h>

typedef __attribute__((ext_vector_type(8))) short bf16x8;
typedef __attribute__((ext_vector_type(4))) float f32x4;

#define DIM   128
#define KD    256
#define FAN   16
#define TILE  16                 // nodes per (single-wave) block
#define XS_STRIDE 264            // shorts per xs row (528 B, 16B-aligned)
#define WP_LAYER_SHORTS (8*8*64*8)   // 32768 shorts = 64 KiB per layer

__device__ __forceinline__ unsigned short f2bf(float f) {
    __hip_bfloat16 h = __float2bfloat16(f);           // RNE
    return *reinterpret_cast<unsigned short*>(&h);
}
__device__ __forceinline__ float bflo(unsigned int u) { return __uint_as_float(u << 16); }
__device__ __forceinline__ float bfhi(unsigned int u) { return __uint_as_float(u & 0xffff0000u); }

// ---- prep: f32 -> packed bf16 (4 elems per uint2) ----
__global__ __launch_bounds__(256)
void cvt_bf16_kernel(const float* __restrict__ in, uint2* __restrict__ out, int n4)
{
    const int stride = gridDim.x * blockDim.x;
    for (int i = blockIdx.x * blockDim.x + threadIdx.x; i < n4; i += stride) {
        const float4 v = reinterpret_cast<const float4*>(in)[i];
        uint2 o;
        o.x = (unsigned int)f2bf(v.x) | ((unsigned int)f2bf(v.y) << 16);
        o.y = (unsigned int)f2bf(v.z) | ((unsigned int)f2bf(v.w) << 16);
        out[i] = o;
    }
}

// ---- pack W (f32 [k][col]) into MFMA B-frag order: wp[t][ks][lane][j] bf16 ----
// frag semantics: lane=(lg<<4)|l15 holds B[k=ks*32+lg*8+j][col=t*16+l15]
__global__ __launch_bounds__(256)
void wpack_kernel(const float* __restrict__ W1, const float* __restrict__ W2,
                  unsigned short* __restrict__ wp)
{
    const int b = blockIdx.x;                  // 0..15: [layer][t]
    const float* W = (b & 8) ? W2 : W1;
    unsigned short* dst = wp + ((b & 8) ? WP_LAYER_SHORTS : 0);
    const int t   = b & 7;
    const int tid = threadIdx.x;
    const int lane = tid & 63, wid = tid >> 6;
    const int l15 = lane & 15, lg = lane >> 4;
    #pragma unroll
    for (int s = 0; s < 2; ++s) {
        const int ks = wid + s * 4;
        bf16x8 v;
        #pragma unroll
        for (int j = 0; j < 8; ++j)
            v[j] = (short)f2bf(W[(size_t)(ks * 32 + lg * 8 + j) * DIM + t * 16 + l15]);
        *reinterpret_cast<bf16x8*>(dst + ((size_t)(t * 8 + ks) * 64 + lane) * 8) = v;
    }
}

// ---- fused SAGE layer, ONE WAVE PER BLOCK (no barriers, scalar idx loads) ----
// Each 64-thread block owns 16 nodes: gather+mean -> bf16 LDS (8.4 KB) -> MFMA
// (1 m-tile x 8 n-tiles, K=256) -> bias+relu. Waves on a SIMD interleave
// independently, so one wave's gather latency hides under others' compute.
template<bool SRC_BF, bool DST_BF>
__global__ __launch_bounds__(64, 5)
void sage_layer(const void* __restrict__ src,                 // [n0][128] bf16 or f32
                const unsigned short* __restrict__ wp,        // frag-packed bf16
                const float* __restrict__ bias,
                const int*  __restrict__ nidx,
                const int*  __restrict__ sidx,
                void* __restrict__ dst,                       // [n][128] bf16 or f32
                int nnodes)
{
    __shared__ unsigned short xs[TILE * XS_STRIDE];           // 8448 B

    const int lane = threadIdx.x;        // block == 1 wave
    const int l15  = lane & 15;
    const int lg   = lane >> 4;
    const int nb   = blockIdx.x * TILE;

    // ---- gather: node index n is block-uniform -> idx loads scalarize ----
    #pragma unroll 4
    for (int i = 0; i < TILE; ++i) {
        int n = nb + i;
        if (n >= nnodes) n = nnodes - 1;
        const int sn = sidx[n];
        const int* nn = nidx + (size_t)n * FAN;
        unsigned int su;
        float ax = 0.f, ay = 0.f;
        if (SRC_BF) {
            const unsigned int* srcu = (const unsigned int*)src;
            su = srcu[(size_t)sn * 64 + lane];
            #pragma unroll
            for (int j = 0; j < FAN; ++j) {
                const unsigned int u = srcu[(size_t)nn[j] * 64 + lane];
                ax += bflo(u); ay += bfhi(u);
            }
        } else {
            const float* srcf = (const float*)src;
            const float2 sv = *reinterpret_cast<const float2*>(srcf + (size_t)sn * DIM + 2 * lane);
            su = (unsigned int)f2bf(sv.x) | ((unsigned int)f2bf(sv.y) << 16);
            #pragma unroll
            for (int j = 0; j < FAN; ++j) {
                const float2 v = *reinterpret_cast<const float2*>(srcf + (size_t)nn[j] * DIM + 2 * lane);
                ax += v.x; ay += v.y;
            }
        }
        ax *= 0.0625f; ay *= 0.0625f;
        const unsigned int mu = (unsigned int)f2bf(ax) | ((unsigned int)f2bf(ay) << 16);
        unsigned int* row = reinterpret_cast<unsigned int*>(xs + (size_t)i * XS_STRIDE);
        row[lane]      = su;   // self half:  k = 2*lane, 2*lane+1
        row[64 + lane] = mu;   // mean half:  k = 128 + 2*lane, +1
    }
    // no __syncthreads: single-wave block, ds ordering via lgkmcnt

    // ---- MFMA: 1 m-tile x 8 n-tiles, K=256 in 8 steps ----
    // unroll 1: keep only one ks's 8 W-fragments (32 VGPR) in flight -> no spill
    f32x4 acc[8];
    #pragma unroll
    for (int t = 0; t < 8; ++t) acc[t] = (f32x4){0.f, 0.f, 0.f, 0.f};

    #pragma unroll 1
    for (int ks = 0; ks < 8; ++ks) {
        const bf16x8 af = *reinterpret_cast<const bf16x8*>(
            xs + (size_t)l15 * XS_STRIDE + ks * 32 + lg * 8);
        #pragma unroll
        for (int t = 0; t < 8; ++t) {
            const bf16x8 w = *reinterpret_cast<const bf16x8*>(
                wp + ((size_t)(t * 8 + ks) * 64 + lane) * 8);
            acc[t] = __builtin_amdgcn_mfma_f32_16x16x32_bf16(af, w, acc[t], 0, 0, 0);
        }
    }

    // ---- epilogue: bias + relu; C/D: col = lane&15, row = (lane>>4)*4 + r ----
    #pragma unroll
    for (int t = 0; t < 8; ++t) {
        const int col = t * 16 + l15;
        const float bvt = bias[col];
        #pragma unroll
        for (int r = 0; r < 4; ++r) {
            const int n = nb + lg * 4 + r;
            if (n < nnodes) {
                const float v = acc[t][r] + bvt;
                const float rv = v > 0.f ? v : 0.f;
                if (DST_BF)
                    ((unsigned short*)dst)[(size_t)n * DIM + col] = f2bf(rv);
                else
                    ((float*)dst)[(size_t)n * DIM + col] = rv;
            }
        }
    }
}

extern "C" void kernel_launch(void* const* d_in, const int* in_sizes, int n_in,
                              void* d_out, int out_size, void* d_ws, size_t ws_size,
                              hipStream_t stream)
{
    const float* features = (const float*)d_in[0];
    const float* W1       = (const float*)d_in[1];
    const float* b1       = (const float*)d_in[2];
    const float* W2       = (const float*)d_in[3];
    const float* b2       = (const float*)d_in[4];
    const int*   n1idx    = (const int*)d_in[5];
    const int*   s1idx    = (const int*)d_in[6];
    const int*   n2idx    = (const int*)d_in[7];
    const int*   s2idx    = (const int*)d_in[8];

    const int NF = in_sizes[0];        // 200000*128
    const int N1 = in_sizes[6];        // 100000
    const int N2 = in_sizes[8];        // 50000

    const size_t fbf_bytes = (size_t)NF * 2;                  // 51.2 MB
    const size_t h1_bytes  = (size_t)N1 * DIM * 2;            // 25.6 MB
    const size_t wp_bytes  = (size_t)2 * WP_LAYER_SHORTS * 2; // 128 KiB
    const bool full = ws_size >= fbf_bytes + h1_bytes + wp_bytes;

    unsigned char* ws = (unsigned char*)d_ws;
    unsigned short* fbf = nullptr;
    unsigned short* h1  = nullptr;
    unsigned short* wpk = nullptr;
    if (full) {
        fbf = (unsigned short*)ws;
        h1  = (unsigned short*)(ws + fbf_bytes);
        wpk = (unsigned short*)(ws + fbf_bytes + h1_bytes);
    } else {
        h1  = (unsigned short*)ws;
        wpk = (unsigned short*)(ws + h1_bytes);
    }

    wpack_kernel<<<16, 256, 0, stream>>>(W1, W2, wpk);
    if (full)
        cvt_bf16_kernel<<<2048, 256, 0, stream>>>(features, (uint2*)fbf, NF / 4);

    const int t1 = (N1 + TILE - 1) / TILE;   // 6250
    const int t2 = (N2 + TILE - 1) / TILE;   // 3125

    if (full)
        sage_layer<true,  true><<<t1, 64, 0, stream>>>(fbf, wpk, b1, n1idx, s1idx, h1, N1);
    else
        sage_layer<false, true><<<t1, 64, 0, stream>>>(features, wpk, b1, n1idx, s1idx, h1, N1);

    sage_layer<true, false><<<t2, 64, 0, stream>>>(h1, wpk + WP_LAYER_SHORTS, b2,
                                                   n2idx, s2idx, (float*)d_out, N2);
}

// Round 9
// 284.441 us; speedup vs baseline: 1.2662x; 1.2662x over previous
//
#include <hip/hip_runtime.h>
#include <hip/hip_bf16.h>

typedef __attribute__((ext_vector_type(8))) short bf16x8;
typedef __attribute__((ext_vector_type(4))) float f32x4;

#define DIM   128
#define KD    256
#define FAN   16
#define TILE  32                 // nodes per block (4 waves x 8 nodes)
#define XS_STRIDE 264            // shorts per xs row (528 B = 33*16, uint4-aligned)
#define WP_LAYER_SHORTS (8*8*64*8)   // 32768 shorts = 64 KiB per layer

__device__ __forceinline__ unsigned short f2bf(float f) {
    __hip_bfloat16 h = __float2bfloat16(f);           // RNE
    return *reinterpret_cast<unsigned short*>(&h);
}
__device__ __forceinline__ float bflo(unsigned int u) { return __uint_as_float(u << 16); }
__device__ __forceinline__ float bfhi(unsigned int u) { return __uint_as_float(u & 0xffff0000u); }

// ---- prep: f32 -> packed bf16 (4 elems per uint2) ----
__global__ __launch_bounds__(256)
void cvt_bf16_kernel(const float* __restrict__ in, uint2* __restrict__ out, int n4)
{
    const int stride = gridDim.x * blockDim.x;
    for (int i = blockIdx.x * blockDim.x + threadIdx.x; i < n4; i += stride) {
        const float4 v = reinterpret_cast<const float4*>(in)[i];
        uint2 o;
        o.x = (unsigned int)f2bf(v.x) | ((unsigned int)f2bf(v.y) << 16);
        o.y = (unsigned int)f2bf(v.z) | ((unsigned int)f2bf(v.w) << 16);
        out[i] = o;
    }
}

// ---- pack W (f32 [k][col]) into MFMA B-frag order: wp[t][ks][lane][j] bf16 ----
// frag semantics: lane=(lg<<4)|l15 holds B[k=ks*32+lg*8+j][col=t*16+l15]
__global__ __launch_bounds__(256)
void wpack_kernel(const float* __restrict__ W1, const float* __restrict__ W2,
                  unsigned short* __restrict__ wp)
{
    const int b = blockIdx.x;                  // 0..15: [layer][t]
    const float* W = (b & 8) ? W2 : W1;
    unsigned short* dst = wp + ((b & 8) ? WP_LAYER_SHORTS : 0);
    const int t   = b & 7;
    const int tid = threadIdx.x;
    const int lane = tid & 63, wid = tid >> 6;
    const int l15 = lane & 15, lg = lane >> 4;
    #pragma unroll
    for (int s = 0; s < 2; ++s) {
        const int ks = wid + s * 4;
        bf16x8 v;
        #pragma unroll
        for (int j = 0; j < 8; ++j)
            v[j] = (short)f2bf(W[(size_t)(ks * 32 + lg * 8 + j) * DIM + t * 16 + l15]);
        *reinterpret_cast<bf16x8*>(dst + ((size_t)(t * 8 + ks) * 64 + lane) * 8) = v;
    }
}

// ---- fused SAGE layer: r5 skeleton (one tile per block, 4 waves) with
// 4x-vectorized gather: lane-group g (16 lanes) owns node g of 4; each uint4
// load instr covers 4 whole 256B rows -> 4x fewer vmem instrs, deeper vmcnt
// pipelining. W fragments re-read from L1 per k-step (no 64-VGPR residency).
template<bool SRC_BF, bool DST_BF>
__global__ __launch_bounds__(256, 6)
void sage_layer(const void* __restrict__ src,                 // [n0][128] bf16 or f32
                const unsigned short* __restrict__ wp,        // frag-packed bf16
                const float* __restrict__ bias,
                const int*  __restrict__ nidx,
                const int*  __restrict__ sidx,
                void* __restrict__ dst,                       // [n][128] bf16 or f32
                int nnodes)
{
    __shared__ __align__(16) unsigned short xs[TILE * XS_STRIDE];   // 16896 B
    __shared__ int nib[4][72];                                       // 1152 B

    const int tid  = threadIdx.x;
    const int lane = tid & 63;
    const int wid  = tid >> 6;
    const int l15  = lane & 15;
    const int lg   = lane >> 4;
    const int nb   = blockIdx.x * TILE;

    if (SRC_BF) {
        // ---- gather, x4 rows per instr: group g = lanes 16g..16g+15 ----
        const int g = lg;           // group 0..3 (node within quad)
        const int s = l15;          // sublane: owns channels 8s..8s+7 (16 B)
        const uint4* srcv = (const uint4*)src;      // one row = 16 uint4

        #pragma unroll 1
        for (int it = 0; it < 2; ++it) {
            const int nbase = nb + wid * 8 + it * 4;
            // stage indices: one vec load covers all 4 nodes' 16 neigh idx
            {
                int n = nbase + g; if (n >= nnodes) n = nnodes - 1;
                nib[wid][g * 17 + s] = nidx[(size_t)n * FAN + s];
                if (lane < 4) {
                    int n2 = nbase + lane; if (n2 >= nnodes) n2 = nnodes - 1;
                    nib[wid][68 + lane] = sidx[n2];
                }
            }
            // self row (1 instr for 4 nodes)
            const int sn = nib[wid][68 + g];
            const uint4 sv = srcv[(size_t)sn * 16 + s];
            // neighbors: 16 instrs for 4 nodes, accumulate 8 ch in f32
            float a0 = 0.f, a1 = 0.f, a2 = 0.f, a3 = 0.f;
            float a4 = 0.f, a5 = 0.f, a6 = 0.f, a7 = 0.f;
            #pragma unroll
            for (int j = 0; j < FAN; ++j) {
                const int nj = nib[wid][g * 17 + j];
                const uint4 v = srcv[(size_t)nj * 16 + s];
                a0 += bflo(v.x); a1 += bfhi(v.x);
                a2 += bflo(v.y); a3 += bfhi(v.y);
                a4 += bflo(v.z); a5 += bfhi(v.z);
                a6 += bflo(v.w); a7 += bfhi(v.w);
            }
            uint4 mv;
            mv.x = (unsigned int)f2bf(a0 * 0.0625f) | ((unsigned int)f2bf(a1 * 0.0625f) << 16);
            mv.y = (unsigned int)f2bf(a2 * 0.0625f) | ((unsigned int)f2bf(a3 * 0.0625f) << 16);
            mv.z = (unsigned int)f2bf(a4 * 0.0625f) | ((unsigned int)f2bf(a5 * 0.0625f) << 16);
            mv.w = (unsigned int)f2bf(a6 * 0.0625f) | ((unsigned int)f2bf(a7 * 0.0625f) << 16);
            const int ln = wid * 8 + it * 4 + g;
            uint4* rowp = reinterpret_cast<uint4*>(xs + (size_t)ln * XS_STRIDE);
            rowp[s]      = sv;   // self: shorts 8s..8s+7
            rowp[16 + s] = mv;   // mean: shorts 128+8s..
        }
    } else {
        // fallback (f32 source): r5's scalar per-node gather
        #pragma unroll 4
        for (int i = 0; i < 8; ++i) {
            int n = nb + wid * 8 + i;
            if (n >= nnodes) n = nnodes - 1;
            const int sn = sidx[n];
            const int* nn = nidx + (size_t)n * FAN;
            const float* srcf = (const float*)src;
            const float2 sv = *reinterpret_cast<const float2*>(srcf + (size_t)sn * DIM + 2 * lane);
            unsigned int su = (unsigned int)f2bf(sv.x) | ((unsigned int)f2bf(sv.y) << 16);
            float ax = 0.f, ay = 0.f;
            #pragma unroll
            for (int j = 0; j < FAN; ++j) {
                const float2 v = *reinterpret_cast<const float2*>(srcf + (size_t)nn[j] * DIM + 2 * lane);
                ax += v.x; ay += v.y;
            }
            ax *= 0.0625f; ay *= 0.0625f;
            const unsigned int mu = (unsigned int)f2bf(ax) | ((unsigned int)f2bf(ay) << 16);
            unsigned int* row = reinterpret_cast<unsigned int*>(xs + (size_t)(wid * 8 + i) * XS_STRIDE);
            row[lane]      = su;
            row[64 + lane] = mu;
        }
    }
    __syncthreads();

    // ---- MFMA: per wave 2 m-subtiles x 2 n-tiles, K=256 in 8 steps ----
    // Launder so wp loads stay in-loop (8 VGPR transient, L1-resident).
    int woff = 0;
    asm volatile("" : "+v"(woff));
    const unsigned short* wpt = wp + woff;

    f32x4 acc[2][2];
    #pragma unroll
    for (int mt = 0; mt < 2; ++mt)
        #pragma unroll
        for (int t = 0; t < 2; ++t)
            acc[mt][t] = (f32x4){0.f, 0.f, 0.f, 0.f};

    const int tg0 = 2 * wid, tg1 = 2 * wid + 1;
    #pragma unroll
    for (int ks = 0; ks < 8; ++ks) {
        const bf16x8 af0 = *reinterpret_cast<const bf16x8*>(
            xs + (size_t)(l15) * XS_STRIDE + ks * 32 + lg * 8);
        const bf16x8 af1 = *reinterpret_cast<const bf16x8*>(
            xs + (size_t)(16 + l15) * XS_STRIDE + ks * 32 + lg * 8);
        const bf16x8 w0 = *reinterpret_cast<const bf16x8*>(
            wpt + ((size_t)(tg0 * 8 + ks) * 64 + lane) * 8);
        const bf16x8 w1 = *reinterpret_cast<const bf16x8*>(
            wpt + ((size_t)(tg1 * 8 + ks) * 64 + lane) * 8);
        acc[0][0] = __builtin_amdgcn_mfma_f32_16x16x32_bf16(af0, w0, acc[0][0], 0, 0, 0);
        acc[1][0] = __builtin_amdgcn_mfma_f32_16x16x32_bf16(af1, w0, acc[1][0], 0, 0, 0);
        acc[0][1] = __builtin_amdgcn_mfma_f32_16x16x32_bf16(af0, w1, acc[0][1], 0, 0, 0);
        acc[1][1] = __builtin_amdgcn_mfma_f32_16x16x32_bf16(af1, w1, acc[1][1], 0, 0, 0);
    }

    // ---- epilogue: bias + relu; C/D: col = lane&15, row = (lane>>4)*4 + r ----
    #pragma unroll
    for (int mt = 0; mt < 2; ++mt) {
        #pragma unroll
        for (int t = 0; t < 2; ++t) {
            const int col = (2 * wid + t) * 16 + l15;
            const float bvt = bias[col];
            #pragma unroll
            for (int r = 0; r < 4; ++r) {
                const int n = nb + mt * 16 + lg * 4 + r;
                if (n < nnodes) {
                    const float v = acc[mt][t][r] + bvt;
                    const float rv = v > 0.f ? v : 0.f;
                    if (DST_BF)
                        ((unsigned short*)dst)[(size_t)n * DIM + col] = f2bf(rv);
                    else
                        ((float*)dst)[(size_t)n * DIM + col] = rv;
                }
            }
        }
    }
}

extern "C" void kernel_launch(void* const* d_in, const int* in_sizes, int n_in,
                              void* d_out, int out_size, void* d_ws, size_t ws_size,
                              hipStream_t stream)
{
    const float* features = (const float*)d_in[0];
    const float* W1       = (const float*)d_in[1];
    const float* b1       = (const float*)d_in[2];
    const float* W2       = (const float*)d_in[3];
    const float* b2       = (const float*)d_in[4];
    const int*   n1idx    = (const int*)d_in[5];
    const int*   s1idx    = (const int*)d_in[6];
    const int*   n2idx    = (const int*)d_in[7];
    const int*   s2idx    = (const int*)d_in[8];

    const int NF = in_sizes[0];        // 200000*128
    const int N1 = in_sizes[6];        // 100000
    const int N2 = in_sizes[8];        // 50000

    const size_t fbf_bytes = (size_t)NF * 2;                  // 51.2 MB
    const size_t h1_bytes  = (size_t)N1 * DIM * 2;            // 25.6 MB
    const size_t wp_bytes  = (size_t)2 * WP_LAYER_SHORTS * 2; // 128 KiB
    const bool full = ws_size >= fbf_bytes + h1_bytes + wp_bytes;

    unsigned char* ws = (unsigned char*)d_ws;
    unsigned short* fbf = nullptr;
    unsigned short* h1  = nullptr;
    unsigned short* wpk = nullptr;
    if (full) {
        fbf = (unsigned short*)ws;
        h1  = (unsigned short*)(ws + fbf_bytes);
        wpk = (unsigned short*)(ws + fbf_bytes + h1_bytes);
    } else {
        h1  = (unsigned short*)ws;
        wpk = (unsigned short*)(ws + h1_bytes);
    }

    wpack_kernel<<<16, 256, 0, stream>>>(W1, W2, wpk);
    if (full)
        cvt_bf16_kernel<<<2048, 256, 0, stream>>>(features, (uint2*)fbf, NF / 4);

    const int t1 = (N1 + TILE - 1) / TILE;   // 3125
    const int t2 = (N2 + TILE - 1) / TILE;   // 1563

    if (full)
        sage_layer<true,  true><<<t1, 256, 0, stream>>>(fbf, wpk, b1, n1idx, s1idx, h1, N1);
    else
        sage_layer<false, true><<<t1, 256, 0, stream>>>(features, wpk, b1, n1idx, s1idx, h1, N1);

    sage_layer<true, false><<<t2, 256, 0, stream>>>(h1, wpk + WP_LAYER_SHORTS, b2,
                                                    n2idx, s2idx, (float*)d_out, N2);
}